// Round 5
// baseline (1336.160 us; speedup 1.0000x reference)
//
#include <hip/hip_runtime.h>
#include <hip/hip_bf16.h>

// MyRnn: h_t = tanh(emb[idx_t] @ W_xh + b_h + h_{t-1} @ W_hh), 80 steps,
// out = sigmoid(h_80 @ W_out + b_out).
//
// R5: ALL-STREAM, spill-proof. Lesson R1-R4: with MFMA present the compiler
// splits the 256-reg/wave unified budget 128 arch / 128 acc and never places
// loaded weight frags in AGPRs -> any design with resident weight registers
// spills (WRITE_SIZE 26-36 MB signature every round). So: ZERO resident
// weights. W_xh (4 ksteps) + W_hh (16 ksteps) stream from L2 every step as a
// unified 20-kstep loop through one rotating sB[SDEPTH][NT] (48 regs peak);
// arch demand ~100 < 128 cap. L2-bound: 640 KB/CU/step * 16 CU/XCD
// = 10.2 MB/step/XCD / 4.3 TB/s ~ 2.4 us/step -> ~195 us total.
// h double-buffers through XOR-swizzled LDS; ONE __syncthreads per step.

#define T_LEN   80
#define EMB_D   100
#define UNITS   512
#define ROWS    16
#define NBLK    128              // 2048/16
#define NTHR    512
#define NT      4                // 16-col n-tiles per wave (64 cols)
#define KSH     16               // hh K-steps (512/32)
#define KSX     4                // x K-steps (128/32, zero-padded)
#define KSALL   (KSX + KSH)      // unified streamed ksteps
#define SDEPTH  3                // streamed pipeline depth

typedef __bf16 bf16x8 __attribute__((ext_vector_type(8)));
typedef float  f32x4  __attribute__((ext_vector_type(4)));

__device__ __forceinline__ float fast_tanh(float x) {
    float e = __builtin_amdgcn_exp2f(x * 2.8853900817779268f);
    return 1.0f - 2.0f * __builtin_amdgcn_rcpf(1.0f + e);
}

// ---- prep: transpose + bf16-cast weights into d_ws ----
// Wt[n=512][k=512], Xt[n=512][k=128] (k>=100 zeroed)
__global__ void prep_kernel(const float* __restrict__ Whh,
                            const float* __restrict__ Wxh,
                            __bf16* __restrict__ Wt, __bf16* __restrict__ Xt) {
    __shared__ float tile[32][33];
    const int tx = threadIdx.x & 31, ty = threadIdx.x >> 5;  // 32x8
    const int b = blockIdx.x;
    if (b < 256) {
        const int k0 = (b & 15) * 32, n0 = (b >> 4) * 32;
        #pragma unroll
        for (int i = 0; i < 4; ++i)
            tile[ty + 8 * i][tx] = Whh[(k0 + ty + 8 * i) * UNITS + n0 + tx];
        __syncthreads();
        #pragma unroll
        for (int i = 0; i < 4; ++i) {
            const int n = ty + 8 * i;
            Wt[(n0 + n) * UNITS + k0 + tx] = (__bf16)tile[tx][n];
        }
    } else {
        const int bb = b - 256;
        const int k0 = (bb & 3) * 32, n0 = (bb >> 2) * 32;
        #pragma unroll
        for (int i = 0; i < 4; ++i) {
            const int k = k0 + ty + 8 * i;
            tile[ty + 8 * i][tx] = (k < EMB_D) ? Wxh[k * UNITS + n0 + tx] : 0.0f;
        }
        __syncthreads();
        #pragma unroll
        for (int i = 0; i < 4; ++i) {
            const int n = ty + 8 * i;
            Xt[(n0 + n) * 128 + k0 + tx] = (__bf16)tile[tx][n];
        }
    }
}

__global__ __launch_bounds__(NTHR)
__attribute__((amdgpu_waves_per_eu(2, 2)))
void rnn_kernel(const int*   __restrict__ inputs,   // [2048][80]
                const float* __restrict__ emb,      // [35000][100]
                const float* __restrict__ bh,       // [512]
                const float* __restrict__ Wout,     // [512]
                const float* __restrict__ bout,     // [1]
                const __bf16* __restrict__ Wt,      // [512 n][512 k] (ws)
                const __bf16* __restrict__ Xt,      // [512 n][128 k] (ws)
                float*       __restrict__ out)      // [2048]
{
    // h: 16 rows x 512 bf16; elem(r,k) = r*512 + (((k>>3)^(r&7))<<3) + (k&7)
    // x: 16 rows x 128 bf16; same swizzle, row stride 128.
    __shared__ alignas(16) __bf16 hbuf[2][ROWS * UNITS];  // 2 x 16 KB
    __shared__ alignas(16) __bf16 xbuf[2][ROWS * 128];    // 2 x 4 KB

    const int tid  = threadIdx.x;
    const int wave = tid >> 6;       // 0..7
    const int lane = tid & 63;
    const int q    = lane >> 4;
    const int ln   = lane & 15;
    const int e7   = ln & 7;
    const int qa   = q ^ (e7 & 3);
    const int kx   = e7 >> 2;
    const int q8   = q << 3;
    const int r0   = blockIdx.x * ROWS;

    // per-nt element offsets: streamed frag (i,nt) =
    //   i<KSX : Xt + xoff[nt] + i*32      (W_xh kstep i)
    //   else  : Wt + woff[nt] + (i-KSX)*32 (W_hh kstep i-KSX)
    int   woff[NT], xoff[NT];
    float bhv[NT];
    #pragma unroll
    for (int nt = 0; nt < NT; ++nt) {
        const int col = (wave << 6) + (nt << 4) + ln;
        woff[nt] = col * UNITS + q8;
        xoff[nt] = col * 128   + q8;
        bhv[nt]  = bh[col];
    }

    // zero LDS: hbuf[0] (h0 = 0) and both xbufs (pad cols k>=100 stay 0)
    {
        int4 z; z.x = z.y = z.z = z.w = 0;
        int4* hp = (int4*)&hbuf[0][0];
        #pragma unroll
        for (int i = 0; i < 4; ++i) hp[tid + i * NTHR] = z;   // 32 KB (both hbufs)
        int4* xp = (int4*)&xbuf[0][0];
        xp[tid] = z;                                          // 8 KB (both xbufs)
    }
    __syncthreads();

    // stage embedded x_t (bf16, swizzled); wave w does rows w and w+8
    auto stage = [&](int t, __bf16* xb) {
        #pragma unroll
        for (int rr = 0; rr < 2; ++rr) {
            const int r = wave + (rr << 3);
            const int idxv = inputs[(r0 + r) * T_LEN + t];
            const float* er = emb + (size_t)idxv * EMB_D;
            const int k0 = lane;          // < 100 always
            xb[(r << 7) + ((((k0 >> 3) ^ (r & 7)) << 3) | (k0 & 7))] = (__bf16)er[k0];
            const int k1 = lane + 64;
            if (k1 < EMB_D)
                xb[(r << 7) + ((((k1 >> 3) ^ (r & 7)) << 3) | (k1 & 7))] = (__bf16)er[k1];
        }
    };

    auto step = [&](const __bf16* hb_r, const __bf16* xb_r, __bf16* hb_w) {
        // rotating streamed-B pipeline, unified over 20 ksteps (4 x + 16 h)
        bf16x8 sB[SDEPTH][NT];
        #pragma unroll
        for (int p = 0; p < SDEPTH; ++p)
            #pragma unroll
            for (int nt = 0; nt < NT; ++nt)
                sB[p][nt] = (p < KSX)
                    ? *(const bf16x8*)(Xt + xoff[nt] + (p << 5))
                    : *(const bf16x8*)(Wt + woff[nt] + ((p - KSX) << 5));

        f32x4 acc[NT];
        #pragma unroll
        for (int nt = 0; nt < NT; ++nt) {
            f32x4 a = {bhv[nt], bhv[nt], bhv[nt], bhv[nt]};
            acc[nt] = a;
        }

        const int xb0 = (ln << 7) + (qa << 3);
        const int hb0 = (ln << 9) + (qa << 3);
        #pragma unroll
        for (int i = 0; i < KSALL; ++i) {
            const int s = i % SDEPTH;
            bf16x8 a;
            if (i < KSX)
                a = *(const bf16x8*)&xb_r[xb0 + ((i ^ kx) << 5)];
            else
                a = *(const bf16x8*)&hb_r[hb0 + (((i - KSX) ^ kx) << 5)];
            #pragma unroll
            for (int nt = 0; nt < NT; ++nt)
                acc[nt] = __builtin_amdgcn_mfma_f32_16x16x32_bf16(a, sB[s][nt], acc[nt], 0, 0, 0);
            if (i + SDEPTH < KSALL) {
                const int j = i + SDEPTH;
                #pragma unroll
                for (int nt = 0; nt < NT; ++nt)
                    sB[s][nt] = (j < KSX)
                        ? *(const bf16x8*)(Xt + xoff[nt] + (j << 5))
                        : *(const bf16x8*)(Wt + woff[nt] + ((j - KSX) << 5));
            }
        }
        // write h': C/D layout col=ln, row=4q+i
        #pragma unroll
        for (int nt = 0; nt < NT; ++nt) {
            const int cc = (wave << 3) + (nt << 1) + (ln >> 3);  // col>>3
            #pragma unroll
            for (int i = 0; i < 4; ++i) {
                const int row = (q << 2) + i;
                hb_w[(row << 9) + (((cc ^ (row & 7)) << 3) | (ln & 7))] =
                    (__bf16)fast_tanh(acc[nt][i]);
            }
        }
    };

    stage(0, xbuf[0]);
    __syncthreads();

    #pragma unroll 1
    for (int t = 0; t < T_LEN; t += 2) {
        stage(t + 1, xbuf[1]);                        // t+1 <= 79
        step(hbuf[0], xbuf[0], hbuf[1]);
        __syncthreads();
        if (t + 2 < T_LEN) stage(t + 2, xbuf[0]);
        step(hbuf[1], xbuf[1], hbuf[0]);
        __syncthreads();
    }
    // h_last in hbuf[0], rows 0..15

    // output head: wave w reduces rows w and w+8
    #pragma unroll
    for (int rr = 0; rr < 2; ++rr) {
        const int m = wave + (rr << 3);
        const bf16x8 hv = *(const bf16x8*)&hbuf[0][(m << 9) + ((lane ^ (m & 7)) << 3)];
        float s = 0.0f;
        #pragma unroll
        for (int j = 0; j < 8; ++j)
            s += (float)hv[j] * Wout[(lane << 3) + j];
        #pragma unroll
        for (int off = 32; off > 0; off >>= 1)
            s += __shfl_down(s, off, 64);
        if (lane == 0) {
            const float logit = s + bout[0];
            out[r0 + m] = __builtin_amdgcn_rcpf(
                1.0f + __builtin_amdgcn_exp2f(-logit * 1.4426950408889634f));
        }
    }
}

extern "C" void kernel_launch(void* const* d_in, const int* in_sizes, int n_in,
                              void* d_out, int out_size, void* d_ws, size_t ws_size,
                              hipStream_t stream) {
    __bf16* Wt = (__bf16*)d_ws;                 // 512*512*2 = 512 KB
    __bf16* Xt = Wt + UNITS * UNITS;            // 512*128*2 = 128 KB
    prep_kernel<<<dim3(320), dim3(256), 0, stream>>>(
        (const float*)d_in[3],   // W_hh
        (const float*)d_in[2],   // W_xh
        Wt, Xt);
    rnn_kernel<<<dim3(NBLK), dim3(NTHR), 0, stream>>>(
        (const int*)d_in[0],     // inputs
        (const float*)d_in[1],   // emb_table
        (const float*)d_in[4],   // b_h
        (const float*)d_in[5],   // W_out
        (const float*)d_in[6],   // b_out
        Wt, Xt,
        (float*)d_out);
}